// Round 1
// baseline (474.339 us; speedup 1.0000x reference)
//
#include <hip/hip_runtime.h>
#include <hip/hip_bf16.h>

#define NB 4
#define CH 128
#define NN 4096          // H*W
#define THR2 256.0f      // dist<16  <=>  d2<256
#define KS 4             // split-K factor for the big GEMMs

typedef short bf16x8 __attribute__((ext_vector_type(8)));
typedef float f32x4 __attribute__((ext_vector_type(4)));
using u16 = unsigned short;

__device__ __forceinline__ u16 f2bf(float v) {
  return __builtin_bit_cast(u16, __float2bfloat16(v));
}
__device__ __forceinline__ float bf2f(u16 u) {
  return __builtin_bit_cast(float, ((unsigned int)u) << 16);
}

// ---------------- WbT[c][d] = bf16(W_fc[d][c]) -------------------------------
__global__ void k_wbt(const float* __restrict__ W, u16* __restrict__ WbT) {
  int t = blockIdx.x * 256 + threadIdx.x;   // 16384
  int c = t >> 7, d = t & 127;
  WbT[c * 128 + d] = f2bf(W[d * 128 + c]);
}

// ---------------- xfb[b][n][c] = bf16(x[b][c][n]);  sq[b][n] = sum_c x^2 -----
__global__ __launch_bounds__(256) void k_prep(const float* __restrict__ x,
                                              u16* __restrict__ xfb,
                                              float* __restrict__ sq) {
  __shared__ float ls[128][65];
  int blk = blockIdx.x;            // NB*64
  int b = blk >> 6;
  int n0 = (blk & 63) * 64;
  int t = threadIdx.x;
  const float* xb = x + (size_t)b * CH * NN;
  {
    int j = t & 63, cb = t >> 6;
#pragma unroll
    for (int i = 0; i < 32; ++i) {
      int c = cb * 32 + i;
      ls[c][j] = xb[(size_t)c * NN + n0 + j];
    }
  }
  __syncthreads();
  int jr = t >> 2, q = t & 3;
  float s = 0.f;
  u16* dst = xfb + ((size_t)b * NN + n0 + jr) * CH + q * 32;
#pragma unroll
  for (int ch = 0; ch < 4; ++ch) {
    unsigned int w[4];
#pragma unroll
    for (int p = 0; p < 4; ++p) {
      float va = ls[q * 32 + ch * 8 + 2 * p][jr];
      float vb = ls[q * 32 + ch * 8 + 2 * p + 1][jr];
      s += va * va + vb * vb;
      w[p] = (unsigned int)f2bf(va) | ((unsigned int)f2bf(vb) << 16);
    }
    ((uint4*)dst)[ch] = make_uint4(w[0], w[1], w[2], w[3]);
  }
  s += __shfl_xor(s, 1);
  s += __shfl_xor(s, 2);
  if (q == 0) sq[b * NN + n0 + jr] = s;
}

// ---------------- xeT[b][d][n] = bf16( sum_c xf[n][c]*W[d][c] + b_fc[d] ) ----
__global__ __launch_bounds__(256) void k_xe(const u16* __restrict__ xfb,
                                            const u16* __restrict__ WbT,
                                            const float* __restrict__ bfc,
                                            u16* __restrict__ xeT) {
  __shared__ char sm[65536];
  float* lsX = (float*)sm;              // [64][128] f32
  u16* lsW = (u16*)(sm + 32768);        // [128][128] bf16
  int blk = blockIdx.x;  int b = blk >> 6;  int n0 = (blk & 63) * 64;
  int t = threadIdx.x;
  {
    int n = t >> 2, q = t & 3;
    const uint4* s4 = (const uint4*)(xfb + ((size_t)b * NN + n0 + n) * CH + q * 32);
    float* dstf = lsX + n * 128 + q * 32;
#pragma unroll
    for (int ch = 0; ch < 4; ++ch) {
      uint4 pk = s4[ch];
      unsigned int vals[4] = {pk.x, pk.y, pk.z, pk.w};
#pragma unroll
      for (int p = 0; p < 4; ++p) {
        dstf[ch * 8 + 2 * p]     = __builtin_bit_cast(float, vals[p] << 16);
        dstf[ch * 8 + 2 * p + 1] = __builtin_bit_cast(float, vals[p] & 0xFFFF0000u);
      }
    }
  }
  {
    int c = t >> 1, half = t & 1;
    const uint4* s = (const uint4*)(WbT + c * 128 + half * 64);
    uint4* d = (uint4*)(lsW + c * 128 + half * 64);
#pragma unroll
    for (int i = 0; i < 8; ++i) d[i] = s[i];
  }
  __syncthreads();
  int d = t & 127, ng = t >> 7;
  float acc[32];
  float bias = bfc[d];
#pragma unroll
  for (int n = 0; n < 32; ++n) acc[n] = bias;
  for (int c4 = 0; c4 < 32; ++c4) {
    float wv[4];
#pragma unroll
    for (int p = 0; p < 4; ++p) wv[p] = bf2f(lsW[(c4 * 4 + p) * 128 + d]);
#pragma unroll
    for (int n = 0; n < 32; ++n) {
      f32x4 xv = *(const f32x4*)(lsX + (ng * 32 + n) * 128 + c4 * 4);
      acc[n] = fmaf(xv[0], wv[0], acc[n]);
      acc[n] = fmaf(xv[1], wv[1], acc[n]);
      acc[n] = fmaf(xv[2], wv[2], acc[n]);
      acc[n] = fmaf(xv[3], wv[3], acc[n]);
    }
  }
  __syncthreads();
  u16* lsO = (u16*)sm;                  // [128][64] reuse
#pragma unroll
  for (int n = 0; n < 32; ++n) lsO[d * 64 + ng * 32 + n] = f2bf(acc[n]);
  __syncthreads();
  {
    int dd = t >> 1, half = t & 1;
    uint4* dst = (uint4*)(xeT + ((size_t)b * CH + dd) * NN + n0 + half * 32);
    const uint4* s = (const uint4*)(lsO + dd * 64 + half * 32);
#pragma unroll
    for (int i = 0; i < 4; ++i) dst[i] = s[i];
  }
}

// ---------------- incidence tile kernel (per batch) --------------------------
// inc[i][j] = (sq[i]+sq[j]-2*dot(xf_i,xf_j) < 256) ? 1 : 0  (bf16 0/1)
// deg[i] += row sums (atomics)
__global__ __launch_bounds__(256) void k_inc(const u16* __restrict__ xfb,
                                             const float* __restrict__ sq,
                                             u16* __restrict__ inc,
                                             float* __restrict__ deg) {
  __shared__ char sm[65536];
  char* lsA = sm;            // [128][128] bf16, row-swizzled
  char* lsB = sm + 32768;
  int t = threadIdx.x;
  int i0 = (blockIdx.x >> 5) * 128;
  int j0 = (blockIdx.x & 31) * 128;
  {
    int row = t >> 1, half = t & 1;
    const uint4* gA = (const uint4*)(xfb + (size_t)(i0 + row) * CH + half * 64);
    const uint4* gB = (const uint4*)(xfb + (size_t)(j0 + row) * CH + half * 64);
    int sw = (row & 7) << 4;
#pragma unroll
    for (int ch = 0; ch < 8; ++ch) {
      int off = row * 256 + half * 128 + ch * 16;
      *(uint4*)(lsA + (off ^ sw)) = gA[ch];
      *(uint4*)(lsB + (off ^ sw)) = gB[ch];
    }
  }
  __syncthreads();
  int w = t >> 6, lane = t & 63;
  int wr = w >> 1, wc = w & 1;
  int lrow = lane & 15, lk = lane >> 4;
  f32x4 zero = {0.f, 0.f, 0.f, 0.f};
  f32x4 acc[4][4];
#pragma unroll
  for (int m = 0; m < 4; ++m)
#pragma unroll
    for (int n = 0; n < 4; ++n) acc[m][n] = zero;
#pragma unroll
  for (int kk = 0; kk < 4; ++kk) {
    int kb = kk * 64 + lk * 16;
    bf16x8 a[4], bfr[4];
#pragma unroll
    for (int m = 0; m < 4; ++m) {
      int row = wr * 64 + m * 16 + lrow;
      a[m] = *(const bf16x8*)(lsA + ((row * 256 + kb) ^ ((row & 7) << 4)));
    }
#pragma unroll
    for (int n = 0; n < 4; ++n) {
      int row = wc * 64 + n * 16 + lrow;
      bfr[n] = *(const bf16x8*)(lsB + ((row * 256 + kb) ^ ((row & 7) << 4)));
    }
#pragma unroll
    for (int m = 0; m < 4; ++m)
#pragma unroll
      for (int n = 0; n < 4; ++n)
        acc[m][n] = __builtin_amdgcn_mfma_f32_16x16x32_bf16(a[m], bfr[n], acc[m][n], 0, 0, 0);
  }
  __syncthreads();
  // threshold -> staged output tile [128][136] u16 (padded stride, 16B-aligned rows)
  u16* lsO = (u16*)sm;
  float sqj[4];
#pragma unroll
  for (int n = 0; n < 4; ++n) sqj[n] = sq[j0 + wc * 64 + n * 16 + lrow];
#pragma unroll
  for (int m = 0; m < 4; ++m) {
#pragma unroll
    for (int r = 0; r < 4; ++r) {
      int irow = wr * 64 + m * 16 + lk * 4 + r;
      float sqi = sq[i0 + irow];
      float rs = 0.f;
#pragma unroll
      for (int n = 0; n < 4; ++n) {
        float d2 = sqi + sqj[n] - 2.0f * acc[m][n][r];
        float v = (d2 < THR2) ? 1.0f : 0.0f;
        rs += v;
        lsO[irow * 136 + wc * 64 + n * 16 + lrow] = (d2 < THR2) ? (u16)0x3F80 : (u16)0;
      }
#pragma unroll
      for (int o = 1; o < 16; o <<= 1) rs += __shfl_xor(rs, o);
      if (lrow == 0) atomicAdd(&deg[i0 + irow], rs);
    }
  }
  __syncthreads();
  {
    int row = t >> 1, half = t & 1;
    uint4* dst = (uint4*)(inc + (size_t)(i0 + row) * NN + j0 + half * 64);
    const uint4* s = (const uint4*)(lsO + row * 136 + half * 64);
#pragma unroll
    for (int ch = 0; ch < 8; ++ch) dst[ch] = s[ch];
  }
}

// ---------------- out[i][d] += sum_k A[i][k]*Bt[d][k]  (split-K, atomics) ----
__global__ __launch_bounds__(256) void k_gemm(const u16* __restrict__ A,   // [NN][NN]
                                              const u16* __restrict__ Bt,  // [128][NN]
                                              float* __restrict__ out) {   // [NN][128]
  __shared__ char sm[24576];
  char* lsA = sm;            // [64][64] bf16 swizzled
  char* lsB = sm + 8192;     // [128][64] bf16 swizzled
  int t = threadIdx.x;
  int mt = blockIdx.x & 63;
  int ks = blockIdx.x >> 6;
  int i0 = mt * 64;
  int k0base = ks * (NN / KS);
  int w = t >> 6, lane = t & 63;
  int wr = w >> 1, wc = w & 1;
  int lrow = lane & 15, lk = lane >> 4;
  f32x4 zero = {0.f, 0.f, 0.f, 0.f};
  f32x4 acc[2][4];
#pragma unroll
  for (int m = 0; m < 2; ++m)
#pragma unroll
    for (int n = 0; n < 4; ++n) acc[m][n] = zero;
  for (int kt = 0; kt < (NN / KS) / 64; ++kt) {
    int k0 = k0base + kt * 64;
    {
      int row = t >> 2, q = t & 3;
      const uint4* src = (const uint4*)(A + (size_t)(i0 + row) * NN + k0 + q * 16);
      int sw = (row & 7) << 4;
      int off = row * 128 + q * 32;
      *(uint4*)(lsA + (off ^ sw)) = src[0];
      *(uint4*)(lsA + ((off + 16) ^ sw)) = src[1];
    }
    {
      int d = t >> 1, half = t & 1;
      const uint4* src = (const uint4*)(Bt + (size_t)d * NN + k0 + half * 32);
      int sw = (d & 7) << 4;
#pragma unroll
      for (int ch = 0; ch < 4; ++ch) {
        int off = d * 128 + half * 64 + ch * 16;
        *(uint4*)(lsB + (off ^ sw)) = src[ch];
      }
    }
    __syncthreads();
#pragma unroll
    for (int kk = 0; kk < 2; ++kk) {
      int kb = kk * 64 + lk * 16;
      bf16x8 a[2], bb[4];
#pragma unroll
      for (int m = 0; m < 2; ++m) {
        int row = wr * 32 + m * 16 + lrow;
        a[m] = *(const bf16x8*)(lsA + ((row * 128 + kb) ^ ((row & 7) << 4)));
      }
#pragma unroll
      for (int n = 0; n < 4; ++n) {
        int row = wc * 64 + n * 16 + lrow;
        bb[n] = *(const bf16x8*)(lsB + ((row * 128 + kb) ^ ((row & 7) << 4)));
      }
#pragma unroll
      for (int m = 0; m < 2; ++m)
#pragma unroll
        for (int n = 0; n < 4; ++n)
          acc[m][n] = __builtin_amdgcn_mfma_f32_16x16x32_bf16(a[m], bb[n], acc[m][n], 0, 0, 0);
    }
    __syncthreads();
  }
#pragma unroll
  for (int m = 0; m < 2; ++m)
#pragma unroll
    for (int r = 0; r < 4; ++r) {
      int irow = i0 + wr * 32 + m * 16 + lk * 4 + r;
#pragma unroll
      for (int n = 0; n < 4; ++n) {
        int d = wc * 64 + n * 16 + lrow;
        atomicAdd(&out[(size_t)irow * 128 + d], acc[m][n][r]);
      }
    }
}

// ---------------- edgeT[d][e] = bf16(edge_f32[e][d]/deg[e]); zero edge_f32 ---
__global__ __launch_bounds__(256) void k_escale(float* __restrict__ ef,
                                                const float* __restrict__ deg,
                                                u16* __restrict__ edgeT) {
  __shared__ u16 lsT[128][72];   // stride 144B (16B-aligned rows)
  int e0 = blockIdx.x * 64;
  int t = threadIdx.x;
  {
    int e = t >> 2, q = t & 3;
    float dv = deg[e0 + e];
    float f = dv > 0.f ? 1.0f / dv : 0.f;
    float* src = ef + (size_t)(e0 + e) * 128 + q * 32;
#pragma unroll
    for (int i = 0; i < 32; ++i) {
      lsT[q * 32 + i][e] = f2bf(src[i] * f);
      src[i] = 0.f;                       // re-zero for next batch's accumulate
    }
  }
  __syncthreads();
  {
    int d = t >> 1, half = t & 1;
    uint4* dst = (uint4*)(edgeT + (size_t)d * NN + e0 + half * 32);
#pragma unroll
    for (int i = 0; i < 4; ++i) dst[i] = *(uint4*)&lsT[d][half * 32 + i * 8];
  }
}

// ---------------- out_pre[b][d][n] = vert/deg + x; accumulate BN sums --------
__global__ __launch_bounds__(256) void k_vfin(const float* __restrict__ vf,
                                              const float* __restrict__ deg,
                                              const float* __restrict__ x,
                                              float* __restrict__ outp,
                                              float* __restrict__ bnsum,
                                              float* __restrict__ bnsq) {
  __shared__ float lsT[128][72];
  int blk = blockIdx.x;  int b = blk >> 6;  int n0 = (blk & 63) * 64;
  int t = threadIdx.x;
  {
    int n = t >> 2, q = t & 3;
    float dv = deg[b * NN + n0 + n];
    float f = dv > 0.f ? 1.0f / dv : 0.f;
    const float* src = vf + ((size_t)b * NN + n0 + n) * 128 + q * 32;
#pragma unroll
    for (int i = 0; i < 32; ++i) lsT[q * 32 + i][n] = src[i] * f;
  }
  __syncthreads();
  {
    int d = t >> 1, half = t & 1;
    const float* xr = x + ((size_t)b * CH + d) * NN + n0 + half * 32;
    float* orow = outp + ((size_t)b * CH + d) * NN + n0 + half * 32;
    float s = 0.f, s2 = 0.f;
#pragma unroll
    for (int i = 0; i < 32; ++i) {
      float v = lsT[d][half * 32 + i] + xr[i];
      orow[i] = v;
      s += v;  s2 += v * v;
    }
    s += __shfl_xor(s, 1);
    s2 += __shfl_xor(s2, 1);
    if (half == 0) { atomicAdd(&bnsum[d], s); atomicAdd(&bnsq[d], s2); }
  }
}

// ---------------- in-place BatchNorm(training) + SiLU ------------------------
__global__ void k_bn(float* __restrict__ y, const float* __restrict__ bnsum,
                     const float* __restrict__ bnsq, const float* __restrict__ gamma,
                     const float* __restrict__ beta) {
  int idx = blockIdx.x * 256 + threadIdx.x;   // 2M
  int d = (idx >> 12) & 127;
  const float cnt = (float)(NB * NN);
  float m = bnsum[d] / cnt;
  float var = bnsq[d] / cnt - m * m;
  float rs = rsqrtf(var + 1e-5f);
  float v = y[idx];
  float tt = (v - m) * rs * gamma[d] + beta[d];
  y[idx] = tt / (1.0f + expf(-tt));
}

extern "C" void kernel_launch(void* const* d_in, const int* in_sizes, int n_in,
                              void* d_out, int out_size, void* d_ws, size_t ws_size,
                              hipStream_t stream) {
  (void)in_sizes; (void)n_in; (void)out_size; (void)ws_size;
  const float* x     = (const float*)d_in[0];
  const float* W     = (const float*)d_in[1];
  const float* bfc   = (const float*)d_in[2];
  const float* gamma = (const float*)d_in[3];
  const float* beta  = (const float*)d_in[4];
  char* ws = (char*)d_ws;
  // zero-init region first (vert_f32 | edge_f32 | deg | bnsum | bnsq)
  float* vert_f32 = (float*)ws;                      // 8 MB  [NB][NN][128]
  float* edge_f32 = (float*)(ws + 8388608);          // 2 MB  [NN][128] (per-batch reuse)
  float* deg      = (float*)(ws + 10485760);         // 64 KB [NB][NN]
  float* bnsum    = (float*)(ws + 10551296);         // 512 B
  float* bnsq     = (float*)(ws + 10551808);         // 512 B
  u16* xfb   = (u16*)(ws + 10552320);                // 4 MB  [NB][NN][128] bf16
  u16* xeT   = (u16*)(ws + 14746624);                // 4 MB  [NB][128][NN] bf16
  u16* edgeT = (u16*)(ws + 18940928);                // 1 MB  [128][NN] bf16 (per-batch)
  u16* WbT   = (u16*)(ws + 19989504);                // 32 KB
  float* sqb = (float*)(ws + 20022272);              // 64 KB [NB][NN]
  u16* incb  = (u16*)(ws + 20087808);                // 32 MB [NN][NN] bf16 (per-batch)

  hipMemsetAsync(d_ws, 0, 10552320, stream);
  k_wbt<<<64, 256, 0, stream>>>(W, WbT);
  k_prep<<<NB * 64, 256, 0, stream>>>(x, xfb, sqb);
  k_xe<<<NB * 64, 256, 0, stream>>>(xfb, WbT, bfc, xeT);
  for (int b = 0; b < NB; ++b) {
    k_inc<<<1024, 256, 0, stream>>>(xfb + (size_t)b * NN * CH, sqb + b * NN,
                                    incb, deg + b * NN);
    k_gemm<<<64 * KS, 256, 0, stream>>>(incb, xeT + (size_t)b * CH * NN, edge_f32);
    k_escale<<<64, 256, 0, stream>>>(edge_f32, deg + b * NN, edgeT);
    k_gemm<<<64 * KS, 256, 0, stream>>>(incb, edgeT, vert_f32 + (size_t)b * NN * CH);
  }
  k_vfin<<<NB * 64, 256, 0, stream>>>(vert_f32, deg, x, (float*)d_out, bnsum, bnsq);
  k_bn<<<2097152 / 256, 256, 0, stream>>>((float*)d_out, bnsum, bnsq, gamma, beta);
}

// Round 4
// 202.654 us; speedup vs baseline: 2.3406x; 2.3406x over previous
//
#include <hip/hip_runtime.h>
#include <hip/hip_bf16.h>

#define NB 4
#define CH 128
#define NN 4096

typedef short bf16x8 __attribute__((ext_vector_type(8)));
typedef float f32x4 __attribute__((ext_vector_type(4)));
typedef float f32x16 __attribute__((ext_vector_type(16)));
using u16 = unsigned short;
using u32 = unsigned int;

__device__ __forceinline__ u16 f2bf(float v) {
  return __builtin_bit_cast(u16, __float2bfloat16(v));
}
__device__ __forceinline__ float bf2f(u16 u) {
  return __builtin_bit_cast(float, ((u32)u) << 16);
}

__device__ __forceinline__ void gld16(const void* g, void* l) {
  __builtin_amdgcn_global_load_lds((const __attribute__((address_space(1))) void*)g,
                                   (__attribute__((address_space(3))) void*)l,
                                   16, 0, 0);
}

// ---------------- WbT[c][d] = bf16(W_fc[d][c]) -------------------------------
__global__ void k_wbt(const float* __restrict__ W, u16* __restrict__ WbT) {
  int t = blockIdx.x * 256 + threadIdx.x;   // 16384
  int c = t >> 7, d = t & 127;
  WbT[c * 128 + d] = f2bf(W[d * 128 + c]);
}

// ---------------- xfb[b][n][c] = bf16(x[b][c][n]);  sq[b][n] = sum_c x^2 -----
__global__ __launch_bounds__(256) void k_prep(const float* __restrict__ x,
                                              u16* __restrict__ xfb,
                                              float* __restrict__ sq) {
  __shared__ float ls[128][65];
  int blk = blockIdx.x;            // NB*64
  int b = blk >> 6;
  int n0 = (blk & 63) * 64;
  int t = threadIdx.x;
  const float* xb = x + (size_t)b * CH * NN;
  {
    int j = t & 63, cb = t >> 6;
#pragma unroll
    for (int i = 0; i < 32; ++i) {
      int c = cb * 32 + i;
      ls[c][j] = xb[(size_t)c * NN + n0 + j];
    }
  }
  __syncthreads();
  int jr = t >> 2, q = t & 3;
  float s = 0.f;
  u16* dst = xfb + ((size_t)b * NN + n0 + jr) * CH + q * 32;
#pragma unroll
  for (int ch = 0; ch < 4; ++ch) {
    u32 w[4];
#pragma unroll
    for (int p = 0; p < 4; ++p) {
      float va = ls[q * 32 + ch * 8 + 2 * p][jr];
      float vb = ls[q * 32 + ch * 8 + 2 * p + 1][jr];
      s += va * va + vb * vb;
      w[p] = (u32)f2bf(va) | ((u32)f2bf(vb) << 16);
    }
    ((uint4*)dst)[ch] = make_uint4(w[0], w[1], w[2], w[3]);
  }
  s += __shfl_xor(s, 1);
  s += __shfl_xor(s, 2);
  if (q == 0) sq[b * NN + n0 + jr] = s;
}

// ---------------- pack XA/XG fragment-order aug arrays -----------------------
// XA[b][vt][slot=k9*2+h][v32][8] : c = k9*16+h*8+j ; aug: [xf, sqh, sql, 1, 1, 0..]
// XG same layout; aug: [-2*xf, 1, 1, sqh, sql, 0..]
__global__ __launch_bounds__(256) void k_pack(const u16* __restrict__ xfb,
                                              const float* __restrict__ sq,
                                              u16* __restrict__ XA,
                                              u16* __restrict__ XG) {
  int bid = blockIdx.x;            // NB*128
  int b = bid >> 7, vt = bid & 127;
  int t = threadIdx.x;
  int v = t >> 3, q = t & 7;
  int row = vt * 32 + v;
  const u16* src = xfb + ((size_t)b * NN + row) * CH;
  size_t tb = ((size_t)b * 128 + vt) * 4608;
  float sv = sq[b * NN + row];
  u16 shi = f2bf(sv);
  u16 slo = f2bf(sv - bf2f(shi));
  const u32 one = 0x3F80u;
  for (int slot = q; slot < 18; slot += 8) {
    int k9 = slot >> 1, h = slot & 1;
    int dsto = (slot * 32 + v) * 8;
    uint4 pa, pg;
    if (k9 < 8) {
      pa = *(const uint4*)(src + k9 * 16 + h * 8);
      u32 w4[4] = {pa.x, pa.y, pa.z, pa.w};
      u32 g4[4];
#pragma unroll
      for (int p = 0; p < 4; ++p) {
        u16 lo = (u16)(w4[p] & 0xFFFF), hi16 = (u16)(w4[p] >> 16);
        u16 glo = f2bf(-2.f * bf2f(lo));
        u16 ghi = f2bf(-2.f * bf2f(hi16));
        g4[p] = (u32)glo | ((u32)ghi << 16);
      }
      pg = make_uint4(g4[0], g4[1], g4[2], g4[3]);
    } else {
      if (h == 0) {
        pa = make_uint4((u32)shi | ((u32)slo << 16), one | (one << 16), 0u, 0u);
        pg = make_uint4(one | (one << 16), (u32)shi | ((u32)slo << 16), 0u, 0u);
      } else {
        pa = make_uint4(0u, 0u, 0u, 0u);
        pg = pa;
      }
    }
    *(uint4*)(XA + tb + dsto) = pa;
    *(uint4*)(XG + tb + dsto) = pg;
  }
}

// ---------------- xe GEMM -> XE2 fragment-order layout -----------------------
// XE2[b][vt][dt4][h2][hi2][d32][8v]
__global__ __launch_bounds__(256) void k_xe(const u16* __restrict__ xfb,
                                            const u16* __restrict__ WbT,
                                            const float* __restrict__ bfc,
                                            u16* __restrict__ XE2) {
  __shared__ char sm[65536];
  float* lsX = (float*)sm;              // [64][128] f32
  u16* lsW = (u16*)(sm + 32768);        // [128][128] bf16
  int blk = blockIdx.x;  int b = blk >> 6;  int n0 = (blk & 63) * 64;
  int t = threadIdx.x;
  {
    int n = t >> 2, q = t & 3;
    const uint4* s4 = (const uint4*)(xfb + ((size_t)b * NN + n0 + n) * CH + q * 32);
    float* dstf = lsX + n * 128 + q * 32;
#pragma unroll
    for (int ch = 0; ch < 4; ++ch) {
      uint4 pk = s4[ch];
      u32 vals[4] = {pk.x, pk.y, pk.z, pk.w};
#pragma unroll
      for (int p = 0; p < 4; ++p) {
        dstf[ch * 8 + 2 * p]     = __builtin_bit_cast(float, vals[p] << 16);
        dstf[ch * 8 + 2 * p + 1] = __builtin_bit_cast(float, vals[p] & 0xFFFF0000u);
      }
    }
  }
  {
    int c = t >> 1, half = t & 1;
    const uint4* s = (const uint4*)(WbT + c * 128 + half * 64);
    uint4* d = (uint4*)(lsW + c * 128 + half * 64);
#pragma unroll
    for (int i = 0; i < 8; ++i) d[i] = s[i];
  }
  __syncthreads();
  int d = t & 127, ng = t >> 7;
  float acc[32];
  float bias = bfc[d];
#pragma unroll
  for (int n = 0; n < 32; ++n) acc[n] = bias;
  for (int c4 = 0; c4 < 32; ++c4) {
    float wv[4];
#pragma unroll
    for (int p = 0; p < 4; ++p) wv[p] = bf2f(lsW[(c4 * 4 + p) * 128 + d]);
#pragma unroll
    for (int n = 0; n < 32; ++n) {
      f32x4 xv = *(const f32x4*)(lsX + (ng * 32 + n) * 128 + c4 * 4);
      acc[n] = fmaf(xv[0], wv[0], acc[n]);
      acc[n] = fmaf(xv[1], wv[1], acc[n]);
      acc[n] = fmaf(xv[2], wv[2], acc[n]);
      acc[n] = fmaf(xv[3], wv[3], acc[n]);
    }
  }
  __syncthreads();
  u16* lsO = (u16*)sm;                  // [128][64] reuse
#pragma unroll
  for (int n = 0; n < 32; ++n) lsO[d * 64 + ng * 32 + n] = f2bf(acc[n]);
  __syncthreads();
  {
    size_t tbv = ((size_t)b * 128 + (n0 >> 5));
#pragma unroll
    for (int it = 0; it < 4; ++it) {
      int cid = t + it * 256;           // 0..1023
      int vtl = cid >> 9, g = cid & 511;
      int dloc = g & 31, hi2 = (g >> 5) & 1, h = (g >> 6) & 1, dt = g >> 7;
      int rowd = dt * 32 + dloc;
      int nl = vtl * 32 + h * 16 + hi2 * 8;
      *(uint4*)(XE2 + ((tbv + vtl) * 512 + g) * 8) = *(const uint4*)(lsO + rowd * 64 + nl);
    }
  }
}

// ---------------- fused: P = (d2<256); out[e][d] += P*B2 ; deg += rowsum(P) --
// blocks: [b 4][et 32][ks 4]; 4 waves; wave covers 32 e rows x 128 d; K over v.
__global__ __launch_bounds__(256, 2) void k_hyp(const u16* __restrict__ XAg,
                                                const u16* __restrict__ XGg,
                                                const u16* __restrict__ B2g,
                                                u16* __restrict__ outP,
                                                float* __restrict__ deg,
                                                int dodeg) {
  __shared__ __align__(16) char smem[34816];
  int t = threadIdx.x;
  int lane = t & 63, w = t >> 6;
  int r = lane & 31, hi = lane >> 5;
  int bid = blockIdx.x;
  int b = bid >> 7, rem = bid & 127;
  int et = rem >> 2, ks = rem & 3;
  int e0 = et * 128;
  int vt0 = ks * 32;

  // B1: xg rows for this wave's 32 e's, all 9 K-slots, in registers
  bf16x8 B1[9];
  {
    const u16* g = XGg + ((size_t)(b * 128 + et * 4 + w)) * 4608 + (hi * 32 + r) * 8;
#pragma unroll
    for (int k9 = 0; k9 < 9; ++k9) B1[k9] = *(const bf16x8*)(g + k9 * 512);
  }

  f32x16 acc2[4];
#pragma unroll
  for (int dt = 0; dt < 4; ++dt)
#pragma unroll
    for (int q = 0; q < 16; ++q) acc2[dt][q] = 0.f;
  float dg = 0.f;

  const u16* xa_t = XAg + ((size_t)(b * 128 + vt0)) * 4608;
  const u16* b2_t = B2g + ((size_t)(b * 128 + vt0)) * 4096;

  // prologue: stage tile 0 into buf 0
  {
    char* L = smem;
    for (int i = w; i < 9; i += 4) gld16(xa_t + i * 512 + lane * 8, L + i * 1024);
    for (int i = w; i < 8; i += 4) gld16(b2_t + i * 512 + lane * 8, L + 9216 + i * 1024);
  }
  __syncthreads();
  int cur = 0;
  for (int tile = 0; tile < 32; ++tile) {
    if (tile + 1 < 32) {
      char* L = smem + (cur ^ 1) * 17408;
      const u16* ga = xa_t + (size_t)(tile + 1) * 4608;
      const u16* gb = b2_t + (size_t)(tile + 1) * 4096;
      for (int i = w; i < 9; i += 4) gld16(ga + i * 512 + lane * 8, L + i * 1024);
      for (int i = w; i < 8; i += 4) gld16(gb + i * 512 + lane * 8, L + 9216 + i * 1024);
    }
    char* LA = smem + cur * 17408;
    char* LB = LA + 9216;
    f32x16 d2;
    {
      bf16x8 a1 = *(const bf16x8*)(LA + lane * 16);
      f32x16 z;
#pragma unroll
      for (int q = 0; q < 16; ++q) z[q] = 0.f;
      d2 = __builtin_amdgcn_mfma_f32_32x32x16_bf16(a1, B1[0], z, 0, 0, 0);
    }
#pragma unroll
    for (int k9 = 1; k9 < 9; ++k9) {
      bf16x8 a1 = *(const bf16x8*)(LA + k9 * 1024 + lane * 16);
      d2 = __builtin_amdgcn_mfma_f32_32x32x16_bf16(a1, B1[k9], d2, 0, 0, 0);
    }
    // threshold -> P (f32 0/1), deg accumulate
    float p[16];
#pragma unroll
    for (int q = 0; q < 16; ++q) {
      p[q] = (d2[q] < 256.f) ? 1.f : 0.f;
      dg += p[q];
    }
    // pack to bf16 + permlane swap -> A2 fragments (T12 pattern)
    u32 c[8];
#pragma unroll
    for (int pr = 0; pr < 8; ++pr)
      asm("v_cvt_pk_bf16_f32 %0, %1, %2" : "=v"(c[pr]) : "v"(p[2 * pr]), "v"(p[2 * pr + 1]));
    asm volatile("v_permlane32_swap_b32 %0, %1" : "+v"(c[0]), "+v"(c[2]));
    asm volatile("v_permlane32_swap_b32 %0, %1" : "+v"(c[1]), "+v"(c[3]));
    asm volatile("v_permlane32_swap_b32 %0, %1" : "+v"(c[4]), "+v"(c[6]));
    asm volatile("v_permlane32_swap_b32 %0, %1" : "+v"(c[5]), "+v"(c[7]));
    uint4 u0 = make_uint4(c[0], c[1], c[2], c[3]);
    uint4 u1 = make_uint4(c[4], c[5], c[6], c[7]);
    bf16x8 A2h0 = __builtin_bit_cast(bf16x8, u0);
    bf16x8 A2h1 = __builtin_bit_cast(bf16x8, u1);
#pragma unroll
    for (int dt = 0; dt < 4; ++dt) {
      bf16x8 b20 = *(const bf16x8*)(LB + dt * 2048 + hi * 512 + r * 16);
      bf16x8 b21 = *(const bf16x8*)(LB + dt * 2048 + 1024 + hi * 512 + r * 16);
      acc2[dt] = __builtin_amdgcn_mfma_f32_32x32x16_bf16(A2h0, b20, acc2[dt], 0, 0, 0);
      acc2[dt] = __builtin_amdgcn_mfma_f32_32x32x16_bf16(A2h1, b21, acc2[dt], 0, 0, 0);
    }
    __syncthreads();
    cur ^= 1;
  }
  if (dodeg) {
    float dtot = dg + __shfl_xor(dg, 32);
    if (hi == 0) atomicAdd(&deg[b * NN + e0 + w * 32 + r], dtot);
  }
  // transpose acc2 -> LDS [128 e][128 d] bf16, then coalesced store
  {
    u16* lsE = (u16*)smem + w * 4096;
#pragma unroll
    for (int dt = 0; dt < 4; ++dt)
#pragma unroll
      for (int q = 0; q < 16; ++q) {
        int e_l = (q & 3) + 8 * (q >> 2) + 4 * hi;
        lsE[e_l * 128 + dt * 32 + r] = f2bf(acc2[dt][q]);
      }
  }
  __syncthreads();
  {
    uint4* g4 = (uint4*)(outP + ((size_t)(ks * NB + b) * NN + e0) * 128);
    const uint4* l4 = (const uint4*)smem;
#pragma unroll
    for (int i = 0; i < 8; ++i) g4[t + i * 256] = l4[t + i * 256];
  }
}

// ---------------- edge partials -> scaled ED2 fragment layout ----------------
__global__ __launch_bounds__(256) void k_escale(const u16* __restrict__ P,
                                                const float* __restrict__ deg,
                                                u16* __restrict__ ED2) {
  int bid = blockIdx.x;   // NB*128
  int b = bid >> 7, et = bid & 127;
  int t = threadIdx.x;
#pragma unroll
  for (int c2 = 0; c2 < 2; ++c2) {
    int g = t + c2 * 256;           // 0..511
    int dloc = g & 31, hi2 = (g >> 5) & 1, h = (g >> 6) & 1, dt = g >> 7;
    int d = dt * 32 + dloc;
    int ebase = et * 32 + h * 16 + hi2 * 8;
    u16 outv[8];
#pragma unroll
    for (int j = 0; j < 8; ++j) {
      int e = ebase + j;
      size_t idx = ((size_t)b * NN + e) * 128 + d;
      float s = bf2f(P[idx]) + bf2f(P[idx + 2097152]) +
                bf2f(P[idx + 2 * 2097152]) + bf2f(P[idx + 3 * 2097152]);
      float dv = deg[b * NN + e];
      float f = dv > 0.f ? 1.0f / dv : 0.f;
      outv[j] = f2bf(s * f);
    }
    *(uint4*)(ED2 + (((size_t)b * 128 + et) * 512 + g) * 8) = *(uint4*)outv;
  }
}

// ---------------- vert partials -> out[b][d][n] + residual + BN stats --------
__global__ __launch_bounds__(256) void k_vfin(const u16* __restrict__ P,
                                              const float* __restrict__ deg,
                                              const float* __restrict__ x,
                                              float* __restrict__ outp,
                                              float* __restrict__ bnsum,
                                              float* __restrict__ bnsq) {
  __shared__ float lsT[128][72];
  int blk = blockIdx.x;  int b = blk >> 6;  int n0 = (blk & 63) * 64;
  int t = threadIdx.x;
  {
    int n = t >> 2, q = t & 3;
    int i = n0 + n;
    float dv = deg[b * NN + i];
    float f = dv > 0.f ? 1.0f / dv : 0.f;
    size_t base = ((size_t)b * NN + i) * 128 + q * 32;
    float vs[32];
#pragma unroll
    for (int j = 0; j < 32; ++j) vs[j] = 0.f;
#pragma unroll
    for (int kss = 0; kss < 4; ++kss) {
      const u16* src = P + (size_t)kss * 2097152 + base;
#pragma unroll
      for (int ch = 0; ch < 4; ++ch) {
        uint4 pk = *(const uint4*)(src + ch * 8);
        u32 wv[4] = {pk.x, pk.y, pk.z, pk.w};
#pragma unroll
        for (int pp = 0; pp < 4; ++pp) {
          vs[ch * 8 + 2 * pp]     += bf2f((u16)(wv[pp] & 0xFFFF));
          vs[ch * 8 + 2 * pp + 1] += bf2f((u16)(wv[pp] >> 16));
        }
      }
    }
#pragma unroll
    for (int j = 0; j < 32; ++j) lsT[q * 32 + j][n] = vs[j] * f;
  }
  __syncthreads();
  {
    int d = t >> 1, half = t & 1;
    const float* xr = x + ((size_t)b * CH + d) * NN + n0 + half * 32;
    float* orow = outp + ((size_t)b * CH + d) * NN + n0 + half * 32;
    float s = 0.f, s2 = 0.f;
#pragma unroll
    for (int i = 0; i < 32; ++i) {
      float v = lsT[d][half * 32 + i] + xr[i];
      orow[i] = v;
      s += v;  s2 += v * v;
    }
    s += __shfl_xor(s, 1);
    s2 += __shfl_xor(s2, 1);
    if (half == 0) { atomicAdd(&bnsum[d], s); atomicAdd(&bnsq[d], s2); }
  }
}

// ---------------- in-place BatchNorm(training) + SiLU ------------------------
__global__ void k_bn(float* __restrict__ y, const float* __restrict__ bnsum,
                     const float* __restrict__ bnsq, const float* __restrict__ gamma,
                     const float* __restrict__ beta) {
  int idx = blockIdx.x * 256 + threadIdx.x;   // 2M
  int d = (idx >> 12) & 127;
  const float cnt = (float)(NB * NN);
  float m = bnsum[d] / cnt;
  float var = bnsq[d] / cnt - m * m;
  float rs = rsqrtf(var + 1e-5f);
  float v = y[idx];
  float tt = (v - m) * rs * gamma[d] + beta[d];
  y[idx] = tt / (1.0f + expf(-tt));
}

extern "C" void kernel_launch(void* const* d_in, const int* in_sizes, int n_in,
                              void* d_out, int out_size, void* d_ws, size_t ws_size,
                              hipStream_t stream) {
  (void)in_sizes; (void)n_in; (void)out_size; (void)ws_size;
  const float* x     = (const float*)d_in[0];
  const float* W     = (const float*)d_in[1];
  const float* bfc   = (const float*)d_in[2];
  const float* gamma = (const float*)d_in[3];
  const float* beta  = (const float*)d_in[4];
  char* ws = (char*)d_ws;
  u16* Pbuf  = (u16*)ws;                       // 16 MB: [ks4][b4][4096][128] bf16
  u16* XA    = (u16*)(ws + 16777216);          // 4.5 MB
  u16* XG    = (u16*)(ws + 21495808);          // 4.5 MB
  u16* XE2   = (u16*)(ws + 26214400);          // 4 MB
  u16* ED2   = (u16*)(ws + 30408704);          // 4 MB
  u16* xfb   = (u16*)(ws + 34603008);          // 4 MB
  u16* WbT   = (u16*)(ws + 38797312);          // 32 KB
  float* sqb = (float*)(ws + 38830080);        // 64 KB
  float* deg = (float*)(ws + 38895616);        // 64 KB
  float* bnsum = (float*)(ws + 38961152);      // 512 B
  float* bnsq  = (float*)(ws + 38961664);      // 512 B

  hipMemsetAsync(ws + 38895616, 0, 66560, stream);   // deg + bnsum + bnsq
  k_wbt<<<64, 256, 0, stream>>>(W, WbT);
  k_prep<<<NB * 64, 256, 0, stream>>>(x, xfb, sqb);
  k_pack<<<NB * 128, 256, 0, stream>>>(xfb, sqb, XA, XG);
  k_xe<<<NB * 64, 256, 0, stream>>>(xfb, WbT, bfc, XE2);
  // pass A: edge_raw = inc * xe ; deg = rowsum(inc)
  k_hyp<<<512, 256, 0, stream>>>(XA, XG, XE2, Pbuf, deg, 1);
  k_escale<<<NB * 128, 256, 0, stream>>>(Pbuf, deg, ED2);
  // pass B: vert_raw = inc * edge_scaled
  k_hyp<<<512, 256, 0, stream>>>(XA, XG, ED2, Pbuf, deg, 0);
  k_vfin<<<NB * 64, 256, 0, stream>>>(Pbuf, deg, x, (float*)d_out, bnsum, bnsq);
  k_bn<<<2097152 / 256, 256, 0, stream>>>((float*)d_out, bnsum, bnsq, gamma, beta);
}